// Round 1
// baseline (143.857 us; speedup 1.0000x reference)
//
#include <hip/hip_runtime.h>
#include <stdint.h>

typedef __attribute__((ext_vector_type(8))) short short8;
typedef __attribute__((ext_vector_type(4))) short short4v;
typedef __attribute__((ext_vector_type(4))) float f32x4;

#define S_LEN 4096
#define NBATCH 2
#define DMODEL 768
#define NH 12
#define HD 64
#define MROWS (S_LEN * NBATCH)   // 8192

__device__ __forceinline__ unsigned short f2bf(float f) {
    unsigned int u = __builtin_bit_cast(unsigned int, f);
    u += 0x7fffu + ((u >> 16) & 1u);       // round-to-nearest-even
    return (unsigned short)(u >> 16);
}

// ---------------- kernel 1: val fp32 -> X bf16 (8192 x 768) ----------------
__global__ __launch_bounds__(256) void cvt_val_kernel(const float* __restrict__ in,
                                                      short* __restrict__ out) {
    size_t i = (size_t)blockIdx.x * 256 + threadIdx.x;   // grid covers exactly n/4
    const f32x4 v = *(const f32x4*)(in + i * 4);
    short4v o;
    o.x = (short)f2bf(v.x); o.y = (short)f2bf(v.y);
    o.z = (short)f2bf(v.z); o.w = (short)f2bf(v.w);
    *(short4v*)(out + i * 4) = o;
}

// ------------- kernel 2: W fp32 (K x N) -> WT bf16 (N x K), 3 weights -------------
__global__ __launch_bounds__(256) void cvt_w_kernel(const float* __restrict__ Wq,
                                                    const float* __restrict__ Wk,
                                                    const float* __restrict__ Wv,
                                                    short* __restrict__ WT) {
    const int z = blockIdx.z;
    const float* W = (z == 0) ? Wq : ((z == 1) ? Wk : Wv);
    const int n  = blockIdx.x * 256 + threadIdx.x;  // gridDim.x = 3 -> n in [0,768)
    const int k0 = blockIdx.y * 8;                  // gridDim.y = 96
    short8 o;
#pragma unroll
    for (int i = 0; i < 8; ++i)
        o[i] = (short)f2bf(W[(size_t)(k0 + i) * DMODEL + n]);   // coalesced across n
    *(short8*)(WT + (size_t)z * DMODEL * DMODEL + (size_t)n * DMODEL + k0) = o;
}

// ---------------- kernel 3: QKV GEMM, bf16 MFMA, 128x128 tile, BK=32 ----------------
// C = X(8192x768) * W(768x768); epilogue: +bias, (q only) *0.125, write bf16 to
// per-head layout [bh][s][e] with m = s*2+b, n = h*64+e.
__global__ __launch_bounds__(256) void gemm_qkv_kernel(
    const short* __restrict__ X, const short* __restrict__ WT,
    const float* __restrict__ bq, const float* __restrict__ bk, const float* __restrict__ bv,
    short* __restrict__ Q, short* __restrict__ K, short* __restrict__ V)
{
    __shared__ __align__(16) short As[128 * 40];   // 40-elem row stride: 2-way-free banks
    __shared__ __align__(16) short Bs[128 * 40];

    const int z  = blockIdx.z;
    const int n0 = blockIdx.x * 128;
    const int m0 = blockIdx.y * 128;
    const int tid = threadIdx.x;
    const int lane = tid & 63;
    const int wid  = tid >> 6;

    const short* W    = WT + (size_t)z * DMODEL * DMODEL;
    const float* bias = (z == 0) ? bq : ((z == 1) ? bk : bv);
    short*       OUT  = (z == 0) ? Q  : ((z == 1) ? K  : V);

    const f32x4 zero4 = {0.f, 0.f, 0.f, 0.f};
    f32x4 acc[4][4];
#pragma unroll
    for (int i = 0; i < 4; ++i)
#pragma unroll
        for (int j = 0; j < 4; ++j) acc[i][j] = zero4;

    // staging assignment: thread covers rows r0 and r0+64, k-segment sg
    const int r0 = tid >> 2;
    const int sg = (tid & 3) * 8;
    const short* gA0 = X + (size_t)(m0 + r0)      * DMODEL + sg;
    const short* gA1 = X + (size_t)(m0 + r0 + 64) * DMODEL + sg;
    const short* gB0 = W + (size_t)(n0 + r0)      * DMODEL + sg;
    const short* gB1 = W + (size_t)(n0 + r0 + 64) * DMODEL + sg;

    const int fr = lane & 15, kg = lane >> 4;
    const int wr = (wid >> 1) * 64, wc = (wid & 1) * 64;

    short8 ra0 = *(const short8*)(gA0);
    short8 ra1 = *(const short8*)(gA1);
    short8 rb0 = *(const short8*)(gB0);
    short8 rb1 = *(const short8*)(gB1);

    for (int kt = 0; kt < DMODEL; kt += 32) {
        __syncthreads();                       // previous compute done
        *(short8*)(As + (r0)      * 40 + sg) = ra0;
        *(short8*)(As + (r0 + 64) * 40 + sg) = ra1;
        *(short8*)(Bs + (r0)      * 40 + sg) = rb0;
        *(short8*)(Bs + (r0 + 64) * 40 + sg) = rb1;
        __syncthreads();                       // tile ready
        if (kt + 32 < DMODEL) {                // prefetch next tile (overlaps MFMA)
            ra0 = *(const short8*)(gA0 + kt + 32);
            ra1 = *(const short8*)(gA1 + kt + 32);
            rb0 = *(const short8*)(gB0 + kt + 32);
            rb1 = *(const short8*)(gB1 + kt + 32);
        }
        short8 af[4], bfv[4];
#pragma unroll
        for (int mi = 0; mi < 4; ++mi)
            af[mi] = *(const short8*)(As + (wr + mi * 16 + fr) * 40 + kg * 8);
#pragma unroll
        for (int ni = 0; ni < 4; ++ni)
            bfv[ni] = *(const short8*)(Bs + (wc + ni * 16 + fr) * 40 + kg * 8);
#pragma unroll
        for (int mi = 0; mi < 4; ++mi)
#pragma unroll
            for (int ni = 0; ni < 4; ++ni)
                acc[mi][ni] = __builtin_amdgcn_mfma_f32_16x16x32_bf16(
                    af[mi], bfv[ni], acc[mi][ni], 0, 0, 0);
    }

    const float scale = (z == 0) ? 0.125f : 1.0f;   // q /= sqrt(64)
#pragma unroll
    for (int mi = 0; mi < 4; ++mi) {
#pragma unroll
        for (int ni = 0; ni < 4; ++ni) {
            const int gn = n0 + wc + ni * 16 + fr;
            const float bval = bias[gn];
            const int hh = gn >> 6, e = gn & 63;
#pragma unroll
            for (int r = 0; r < 4; ++r) {
                const int gm = m0 + wr + mi * 16 + 4 * kg + r;  // C/D row = 4*(l>>4)+reg
                const int s = gm >> 1, bb = gm & 1;
                const float v = (acc[mi][ni][r] + bval) * scale;
                OUT[((size_t)(bb * NH + hh) * S_LEN + s) * HD + e] = (short)f2bf(v);
            }
        }
    }
}

// ---------------- kernel 4: V [bh][s][e] -> Vt [bh][e][s] ----------------
__global__ __launch_bounds__(256) void transpose_v_kernel(const short* __restrict__ V,
                                                          short* __restrict__ Vt) {
    __shared__ __align__(16) short T[64][72];
    const int bh = blockIdx.x;          // 24
    const int s0 = blockIdx.y * 64;     // 64 chunks
    const int t  = threadIdx.x;
    const short* Vb  = V  + (size_t)bh * S_LEN * HD;
    short*       Vtb = Vt + (size_t)bh * HD * S_LEN;

    const int sl = t >> 3, e0 = (t & 7) * 8;
#pragma unroll
    for (int i = 0; i < 2; ++i) {
        short8 v = *(const short8*)(Vb + (size_t)(s0 + sl + i * 32) * HD + e0);
        *(short8*)(&T[sl + i * 32][e0]) = v;
    }
    __syncthreads();
    const int e  = t & 63;
    const int sb = (t >> 6) * 16;       // all 64 lanes of a wave share sb -> row-broadcast reads
    short vv[16];
#pragma unroll
    for (int j = 0; j < 16; ++j) vv[j] = T[sb + j][e];
    short8 a, b;
#pragma unroll
    for (int j = 0; j < 8; ++j) { a[j] = vv[j]; b[j] = vv[8 + j]; }
    *(short8*)(Vtb + (size_t)e * S_LEN + s0 + sb)     = a;
    *(short8*)(Vtb + (size_t)e * S_LEN + s0 + sb + 8) = b;
}

// ---------------- kernel 5: banded causal attention ----------------
// One wave per 16-query tile. Window keys [qt-256, qt+32) = 18 tiles of 16 (tail masked).
// QK^T and PV via mfma_f32_16x16x32_bf16; P round-trips through LDS for layout change.
__global__ __launch_bounds__(256) void attn_kernel(
    const short* __restrict__ Q, const short* __restrict__ K,
    const short* __restrict__ Vt, float* __restrict__ out)
{
    __shared__ __align__(16) short P[4][16][296];   // per-wave P tile, padded rows
    const int tid = threadIdx.x, lane = tid & 63, wid = tid >> 6;
    const int qt = (blockIdx.x * 4 + wid) * 16;
    const int bh = blockIdx.y;
    const int bb = bh / NH, hh = bh % NH;
    const int fr = lane & 15, g = lane >> 4;

    const short* Qb = Q  + (size_t)bh * S_LEN * HD;
    const short* Kb = K  + (size_t)bh * S_LEN * HD;
    const short* Vb = Vt + (size_t)bh * HD * S_LEN;

    // A = Q fragment: row = fr (query), k = 8g+i (+32 for second half)
    const short8 qa0 = *(const short8*)(Qb + (size_t)(qt + fr) * HD + g * 8);
    const short8 qa1 = *(const short8*)(Qb + (size_t)(qt + fr) * HD + 32 + g * 8);

    const int j0 = qt - 256;
    float sc[18][4];
#pragma unroll
    for (int t = 0; t < 18; ++t) {
        const int key = j0 + t * 16 + fr;
        const int kc = (key < 0) ? 0 : ((key > S_LEN - 1) ? (S_LEN - 1) : key);
        const short8 kb0 = *(const short8*)(Kb + (size_t)kc * HD + g * 8);
        const short8 kb1 = *(const short8*)(Kb + (size_t)kc * HD + 32 + g * 8);
        f32x4 d = {0.f, 0.f, 0.f, 0.f};
        d = __builtin_amdgcn_mfma_f32_16x16x32_bf16(qa0, kb0, d, 0, 0, 0);
        d = __builtin_amdgcn_mfma_f32_16x16x32_bf16(qa1, kb1, d, 0, 0, 0);
#pragma unroll
        for (int r = 0; r < 4; ++r) {
            const int qi = qt + 4 * g + r;                       // D row = 4g+r
            const bool ok = (key >= 0) & (key <= qi) & (key >= qi - 256);
            sc[t][r] = ok ? d[r] : -1e30f;
        }
    }

    // row softmax: reduce over 16 lanes (key axis) x 18 tiles
    float mx[4], sm[4];
#pragma unroll
    for (int r = 0; r < 4; ++r) {
        float m = sc[0][r];
#pragma unroll
        for (int t = 1; t < 18; ++t) m = fmaxf(m, sc[t][r]);
#pragma unroll
        for (int d_ = 1; d_ < 16; d_ <<= 1) m = fmaxf(m, __shfl_xor(m, d_));
        mx[r] = m;
    }
#pragma unroll
    for (int r = 0; r < 4; ++r) {
        float s_ = 0.f;
#pragma unroll
        for (int t = 0; t < 18; ++t) {
            const float p = __expf(sc[t][r] - mx[r]);
            sc[t][r] = p;
            s_ += p;
        }
#pragma unroll
        for (int d_ = 1; d_ < 16; d_ <<= 1) s_ += __shfl_xor(s_, d_);
        sm[r] = s_;
    }

    // P -> LDS as [q][key] bf16 (A-operand layout for PV)
#pragma unroll
    for (int t = 0; t < 18; ++t)
#pragma unroll
        for (int r = 0; r < 4; ++r)
            P[wid][4 * g + r][t * 16 + fr] = (short)f2bf(sc[t][r]);
    __syncthreads();

    // PV: A = P (16q x 32keys chunks), B = Vt (32keys x 16e), accumulate over 9 chunks
    f32x4 o[4];
#pragma unroll
    for (int et = 0; et < 4; ++et) o[et] = (f32x4){0.f, 0.f, 0.f, 0.f};
#pragma unroll
    for (int c = 0; c < 9; ++c) {
        const short8 pa = *(const short8*)(&P[wid][fr][c * 32 + g * 8]);
        int ka = j0 + c * 32 + g * 8;
        ka = (ka < 0) ? 0 : ((ka > S_LEN - 8) ? (S_LEN - 8) : ka);  // masked keys have p=0
#pragma unroll
        for (int et = 0; et < 4; ++et) {
            const short8 vb = *(const short8*)(Vb + (size_t)(et * 16 + fr) * S_LEN + ka);
            o[et] = __builtin_amdgcn_mfma_f32_16x16x32_bf16(pa, vb, o[et], 0, 0, 0);
        }
    }

    float inv[4];
#pragma unroll
    for (int r = 0; r < 4; ++r) inv[r] = 1.0f / sm[r];
#pragma unroll
    for (int et = 0; et < 4; ++et)
#pragma unroll
        for (int r = 0; r < 4; ++r) {
            const int qi = qt + 4 * g + r;
            const int dd = hh * HD + et * 16 + fr;
            out[((size_t)qi * NBATCH + bb) * DMODEL + dd] = o[et][r] * inv[r];
        }
}

extern "C" void kernel_launch(void* const* d_in, const int* in_sizes, int n_in,
                              void* d_out, int out_size, void* d_ws, size_t ws_size,
                              hipStream_t stream) {
    (void)in_sizes; (void)n_in; (void)out_size; (void)ws_size;
    const float* val = (const float*)d_in[0];
    const float* Wq  = (const float*)d_in[1];
    const float* bq  = (const float*)d_in[2];
    const float* Wk  = (const float*)d_in[3];
    const float* bk  = (const float*)d_in[4];
    const float* Wv  = (const float*)d_in[5];
    const float* bv  = (const float*)d_in[6];
    float* out = (float*)d_out;

    char* ws = (char*)d_ws;
    const size_t SZ_X  = (size_t)MROWS * DMODEL * 2;        // 12,582,912
    const size_t SZ_W  = (size_t)DMODEL * DMODEL * 2;       //  1,179,648
    short* X  = (short*)(ws);
    short* WT = (short*)(ws + SZ_X);
    short* Qb = (short*)(ws + SZ_X + 3 * SZ_W);
    short* Kb = (short*)(ws + SZ_X + 3 * SZ_W + SZ_X);
    short* Vb = (short*)(ws + SZ_X + 3 * SZ_W + 2 * SZ_X);
    short* Vt = (short*)(ws + SZ_X + 3 * SZ_W + 3 * SZ_X);  // total 66.5 MB

    cvt_val_kernel<<<dim3((MROWS * DMODEL) / 4 / 256), dim3(256), 0, stream>>>(val, X);
    cvt_w_kernel<<<dim3(3, 96, 3), dim3(256), 0, stream>>>(Wq, Wk, Wv, WT);
    gemm_qkv_kernel<<<dim3(DMODEL / 128, MROWS / 128, 3), dim3(256), 0, stream>>>(
        X, WT, bq, bk, bv, Qb, Kb, Vb);
    transpose_v_kernel<<<dim3(NBATCH * NH, S_LEN / 64), dim3(256), 0, stream>>>(Vb, Vt);
    attn_kernel<<<dim3(S_LEN / 16 / 4, NBATCH * NH), dim3(256), 0, stream>>>(Qb, Kb, Vt, out);
}

// Round 2
// 106.568 us; speedup vs baseline: 1.3499x; 1.3499x over previous
//
#include <hip/hip_runtime.h>
#include <stdint.h>

typedef __attribute__((ext_vector_type(8))) short short8;
typedef __attribute__((ext_vector_type(4))) short short4v;
typedef __attribute__((ext_vector_type(4))) float f32x4;
typedef __attribute__((ext_vector_type(2))) unsigned int uint2v;

#define S_LEN 4096
#define NBATCH 2
#define DMODEL 768
#define NH 12
#define HD 64
#define MROWS (S_LEN * NBATCH)   // 8192

__device__ __forceinline__ unsigned short f2bf(float f) {
    unsigned int u = __builtin_bit_cast(unsigned int, f);
    u += 0x7fffu + ((u >> 16) & 1u);       // round-to-nearest-even
    return (unsigned short)(u >> 16);
}

// async global->LDS, 16B per lane; LDS dst is wave-uniform base + lane*16
#define GLDS16(gp, lp) __builtin_amdgcn_global_load_lds( \
    (const __attribute__((address_space(1))) void*)(gp), \
    (__attribute__((address_space(3))) void*)(lp), 16, 0, 0)

// ---------------- kernel 1: val fp32 -> X bf16 (8192 x 768) ----------------
__global__ __launch_bounds__(256) void cvt_val_kernel(const float* __restrict__ in,
                                                      short* __restrict__ out) {
    size_t i = (size_t)blockIdx.x * 256 + threadIdx.x;
    const f32x4 v = *(const f32x4*)(in + i * 4);
    short4v o;
    o.x = (short)f2bf(v.x); o.y = (short)f2bf(v.y);
    o.z = (short)f2bf(v.z); o.w = (short)f2bf(v.w);
    *(short4v*)(out + i * 4) = o;
}

// ------------- kernel 2: W fp32 (K x N) -> WT bf16 (N x K), 3 weights -------------
__global__ __launch_bounds__(256) void cvt_w_kernel(const float* __restrict__ Wq,
                                                    const float* __restrict__ Wk,
                                                    const float* __restrict__ Wv,
                                                    short* __restrict__ WT) {
    const int z = blockIdx.z;
    const float* W = (z == 0) ? Wq : ((z == 1) ? Wk : Wv);
    const int n  = blockIdx.x * 256 + threadIdx.x;
    const int k0 = blockIdx.y * 8;
    short8 o;
#pragma unroll
    for (int i = 0; i < 8; ++i)
        o[i] = (short)f2bf(W[(size_t)(k0 + i) * DMODEL + n]);
    *(short8*)(WT + (size_t)z * DMODEL * DMODEL + (size_t)n * DMODEL + k0) = o;
}

// ---------------- kernel 3: QKV GEMM, 128x128 tile, BK=32, global_load_lds ----------------
__global__ __launch_bounds__(256) void gemm_qkv_kernel(
    const short* __restrict__ X, const short* __restrict__ WT,
    const float* __restrict__ bq, const float* __restrict__ bk, const float* __restrict__ bv,
    short* __restrict__ Q, short* __restrict__ K, short* __restrict__ V)
{
    __shared__ __align__(16) short As[2][128 * 32];   // linear: glds needs contiguous dst
    __shared__ __align__(16) short Bs[2][128 * 32];

    const int z  = blockIdx.z;
    const int n0 = blockIdx.x * 128;
    const int m0 = blockIdx.y * 128;
    const int tid = threadIdx.x;
    const int lane = tid & 63;
    const int wid  = tid >> 6;

    const short* W    = WT + (size_t)z * DMODEL * DMODEL;
    const float* bias = (z == 0) ? bq : ((z == 1) ? bk : bv);
    short*       OUT  = (z == 0) ? Q  : ((z == 1) ? K  : V);

    const f32x4 zero4 = {0.f, 0.f, 0.f, 0.f};
    f32x4 acc[4][4];
#pragma unroll
    for (int i = 0; i < 4; ++i)
#pragma unroll
        for (int j = 0; j < 4; ++j) acc[i][j] = zero4;

    // staging: wave covers 32 rows (2 issues of 16); lane -> (row = l>>2, col = (l&3)*8)
    const int lr = lane >> 2;
    const int lc = (lane & 3) * 8;
    const short* gA = X + (size_t)(m0 + wid * 32 + lr) * DMODEL + lc;
    const short* gB = W + (size_t)(n0 + wid * 32 + lr) * DMODEL + lc;

    const int fr = lane & 15, kg = lane >> 4;
    const int wr = (wid >> 1) * 64, wc = (wid & 1) * 64;

#define STAGE(buf, kt) do { \
        GLDS16(gA + (kt),               &As[buf][wid * 1024]);        \
        GLDS16(gA + 16 * DMODEL + (kt), &As[buf][wid * 1024 + 512]);  \
        GLDS16(gB + (kt),               &Bs[buf][wid * 1024]);        \
        GLDS16(gB + 16 * DMODEL + (kt), &Bs[buf][wid * 1024 + 512]);  \
    } while (0)

    STAGE(0, 0);
    int cur = 0;
    for (int kt = 0; kt < DMODEL; kt += 32) {
        __syncthreads();                          // drains vmcnt -> buf[cur] ready
        if (kt + 32 < DMODEL) STAGE(cur ^ 1, kt + 32);   // in flight during MFMA
        short8 af[4], bfv[4];
#pragma unroll
        for (int mi = 0; mi < 4; ++mi)
            af[mi] = *(const short8*)(&As[cur][(wr + mi * 16 + fr) * 32 + kg * 8]);
#pragma unroll
        for (int ni = 0; ni < 4; ++ni)
            bfv[ni] = *(const short8*)(&Bs[cur][(wc + ni * 16 + fr) * 32 + kg * 8]);
#pragma unroll
        for (int mi = 0; mi < 4; ++mi)
#pragma unroll
            for (int ni = 0; ni < 4; ++ni)
                acc[mi][ni] = __builtin_amdgcn_mfma_f32_16x16x32_bf16(
                    af[mi], bfv[ni], acc[mi][ni], 0, 0, 0);
        cur ^= 1;
    }
#undef STAGE

    const float scale = (z == 0) ? 0.125f : 1.0f;   // q /= sqrt(64)
#pragma unroll
    for (int mi = 0; mi < 4; ++mi) {
#pragma unroll
        for (int ni = 0; ni < 4; ++ni) {
            const int gn = n0 + wc + ni * 16 + fr;
            const float bval = bias[gn];
            const int hh = gn >> 6, e = gn & 63;
#pragma unroll
            for (int r = 0; r < 4; ++r) {
                const int gm = m0 + wr + mi * 16 + 4 * kg + r;  // C/D row = 4*(l>>4)+reg
                const int s = gm >> 1, bb = gm & 1;
                const float v = (acc[mi][ni][r] + bval) * scale;
                OUT[((size_t)(bb * NH + hh) * S_LEN + s) * HD + e] = (short)f2bf(v);
            }
        }
    }
}

// ---------------- kernel 4: V [bh][s][e] -> Vt [bh][e][s] ----------------
__global__ __launch_bounds__(256) void transpose_v_kernel(const short* __restrict__ V,
                                                          short* __restrict__ Vt) {
    __shared__ __align__(16) short T[64][72];
    const int bh = blockIdx.x;
    const int s0 = blockIdx.y * 64;
    const int t  = threadIdx.x;
    const short* Vb  = V  + (size_t)bh * S_LEN * HD;
    short*       Vtb = Vt + (size_t)bh * HD * S_LEN;

    const int sl = t >> 3, e0 = (t & 7) * 8;
#pragma unroll
    for (int i = 0; i < 2; ++i) {
        short8 v = *(const short8*)(Vb + (size_t)(s0 + sl + i * 32) * HD + e0);
        *(short8*)(&T[sl + i * 32][e0]) = v;
    }
    __syncthreads();
    const int e  = t & 63;
    const int sb = (t >> 6) * 16;
    short vv[16];
#pragma unroll
    for (int j = 0; j < 16; ++j) vv[j] = T[sb + j][e];
    short8 a, b;
#pragma unroll
    for (int j = 0; j < 8; ++j) { a[j] = vv[j]; b[j] = vv[8 + j]; }
    *(short8*)(Vtb + (size_t)e * S_LEN + s0 + sb)     = a;
    *(short8*)(Vtb + (size_t)e * S_LEN + s0 + sb + 8) = b;
}

// ---------------- kernel 5: banded causal attention, 8 waves x 16 queries ----------------
// Block: 128 queries [q0,q0+128), staged keys [q0-256, q0+128) = 384.
// Swapped QK^T: D = K*Q^T -> col=query(fr), row=key(4g+r). Exactly 17 key-tiles/wave.
#define QB   128
#define KWIN 384
#define KST  72     // K LDS row stride (elems): 144B -> 4-bank rotation per row
#define VST  392    // Vt LDS row stride: 784B -> 4-bank rotation per row
#define PCST 40     // P chunk buffer row stride (80B, 16B-aligned rows)

__global__ __launch_bounds__(512, 2) void attn_kernel(
    const short* __restrict__ Q, const short* __restrict__ K,
    const short* __restrict__ Vt, float* __restrict__ out)
{
    __shared__ __align__(16) short Ks[KWIN * KST];        // 55296 B
    __shared__ __align__(16) short Vs[HD * VST];          // 50176 B
    __shared__ __align__(16) short Pc[8][2][16 * PCST];   // 20480 B  (per-wave ping-pong)

    const int tid = threadIdx.x, lane = tid & 63, wid = tid >> 6;
    const int q0 = blockIdx.x * QB;
    const int bh = blockIdx.y;
    const int bb = bh / NH, hh = bh % NH;
    const int fr = lane & 15, g = lane >> 4;
    const int kstart = q0 - 256;

    const short* Qb = Q  + (size_t)bh * S_LEN * HD;
    const short* Kb = K  + (size_t)bh * S_LEN * HD;
    const short* Vb = Vt + (size_t)bh * HD * S_LEN;

    // ---- cooperative staging (coalesced 16B segments) ----
#pragma unroll
    for (int it = 0; it < 6; ++it) {                 // K: 384 rows x 64 elems
        const int seg = it * 512 + tid;
        const int row = seg >> 3, c8 = (seg & 7) * 8;
        int sr = kstart + row; sr = sr < 0 ? 0 : sr;  // garbage rows masked later
        *(short8*)(Ks + row * KST + c8) = *(const short8*)(Kb + (size_t)sr * HD + c8);
    }
#pragma unroll
    for (int it = 0; it < 6; ++it) {                 // Vt: 64 rows x 384 key-cols
        const int seg = it * 512 + tid;
        const int row = seg / 48, cc = seg % 48;
        int sk = kstart + cc * 8; sk = sk < 0 ? 0 : sk;
        *(short8*)(Vs + row * VST + cc * 8) = *(const short8*)(Vb + (size_t)row * S_LEN + sk);
    }
    __syncthreads();

    // ---- Q fragments (B-operand: col=query=fr, k=8g+i) ----
    const int qrow = q0 + wid * 16 + fr;
    const short8 qa0 = *(const short8*)(Qb + (size_t)qrow * HD + g * 8);
    const short8 qa1 = *(const short8*)(Qb + (size_t)qrow * HD + 32 + g * 8);

    // ---- QK^T: 17 tiles ----
    float sc[17][4];
#pragma unroll
    for (int t = 0; t < 17; ++t) {
        const short* kr = Ks + ((wid + t) * 16 + fr) * KST;   // A row = key
        const short8 a0 = *(const short8*)(kr + g * 8);
        const short8 a1 = *(const short8*)(kr + 32 + g * 8);
        f32x4 d = {0.f, 0.f, 0.f, 0.f};
        d = __builtin_amdgcn_mfma_f32_16x16x32_bf16(a0, qa0, d, 0, 0, 0);
        d = __builtin_amdgcn_mfma_f32_16x16x32_bf16(a1, qa1, d, 0, 0, 0);
        const int gk0 = kstart + (wid + t) * 16 + 4 * g;      // global key (+r)
#pragma unroll
        for (int r = 0; r < 4; ++r) {
            const int dd = 256 + fr - 16 * t - 4 * g - r;     // query - key
            const bool ok = (dd >= 0) & (dd <= 256) & (gk0 + r >= 0);
            sc[t][r] = ok ? d[r] : -1e30f;
        }
    }

    // ---- softmax max (row = query = fr; reduce across g-groups) ----
    float mx = -1e30f;
#pragma unroll
    for (int t = 0; t < 17; ++t)
#pragma unroll
        for (int r = 0; r < 4; ++r) mx = fmaxf(mx, sc[t][r]);
    mx = fmaxf(mx, __shfl_xor(mx, 16));
    mx = fmaxf(mx, __shfl_xor(mx, 32));

    // ---- chunked exp + P redistribute (per-wave LDS, no barrier) + PV ----
    float sm = 0.f;
    f32x4 o[4];
#pragma unroll
    for (int et = 0; et < 4; ++et) o[et] = (f32x4){0.f, 0.f, 0.f, 0.f};

#pragma unroll
    for (int c = 0; c < 9; ++c) {
        float pv[8];
#pragma unroll
        for (int j = 0; j < 8; ++j) {
            const int t = 2 * c + (j >> 2);
            pv[j] = (t < 17) ? __expf(sc[t][j & 3] - mx) : 0.f;   // masked -> exp(-1e30)=0
            sm += pv[j];
        }
        unsigned int u0 = (unsigned)f2bf(pv[0]) | ((unsigned)f2bf(pv[1]) << 16);
        unsigned int u1 = (unsigned)f2bf(pv[2]) | ((unsigned)f2bf(pv[3]) << 16);
        unsigned int u2 = (unsigned)f2bf(pv[4]) | ((unsigned)f2bf(pv[5]) << 16);
        unsigned int u3 = (unsigned)f2bf(pv[6]) | ((unsigned)f2bf(pv[7]) << 16);
        short* pb = &Pc[wid][c & 1][0];
        *(uint2v*)(pb + fr * PCST + 4 * g)      = (uint2v){u0, u1};  // keys 4g..4g+3 (tile 2c)
        *(uint2v*)(pb + fr * PCST + 16 + 4 * g) = (uint2v){u2, u3};  // keys 16+4g..  (tile 2c+1)
        const short8 pa = *(const short8*)(pb + fr * PCST + 8 * g);  // A-frag: q=fr, k=8g..
        int ka = wid * 16 + 32 * c + 8 * g;
        ka = ka > KWIN - 8 ? KWIN - 8 : ka;        // clamped lanes have P=0
#pragma unroll
        for (int et = 0; et < 4; ++et) {
            const short8 vb = *(const short8*)(Vs + (et * 16 + fr) * VST + ka);
            o[et] = __builtin_amdgcn_mfma_f32_16x16x32_bf16(pa, vb, o[et], 0, 0, 0);
        }
    }

    sm += __shfl_xor(sm, 16);
    sm += __shfl_xor(sm, 32);
    const float inv = 1.0f / sm;                   // valid for query = fr
    float inv4[4];
#pragma unroll
    for (int r = 0; r < 4; ++r) inv4[r] = __shfl(inv, 4 * g + r);   // PV D-row = query 4g+r

#pragma unroll
    for (int et = 0; et < 4; ++et)
#pragma unroll
        for (int r = 0; r < 4; ++r) {
            const int qi = q0 + wid * 16 + 4 * g + r;
            const int dd = hh * HD + et * 16 + fr;
            out[((size_t)qi * NBATCH + bb) * DMODEL + dd] = o[et][r] * inv4[r];
        }
}

extern "C" void kernel_launch(void* const* d_in, const int* in_sizes, int n_in,
                              void* d_out, int out_size, void* d_ws, size_t ws_size,
                              hipStream_t stream) {
    (void)in_sizes; (void)n_in; (void)out_size; (void)ws_size;
    const float* val = (const float*)d_in[0];
    const float* Wq  = (const float*)d_in[1];
    const float* bq  = (const float*)d_in[2];
    const float* Wk  = (const float*)d_in[3];
    const float* bk  = (const float*)d_in[4];
    const float* Wv  = (const float*)d_in[5];
    const float* bv  = (const float*)d_in[6];
    float* out = (float*)d_out;

    char* ws = (char*)d_ws;
    const size_t SZ_X  = (size_t)MROWS * DMODEL * 2;
    const size_t SZ_W  = (size_t)DMODEL * DMODEL * 2;
    short* X  = (short*)(ws);
    short* WT = (short*)(ws + SZ_X);
    short* Qb = (short*)(ws + SZ_X + 3 * SZ_W);
    short* Kb = (short*)(ws + SZ_X + 3 * SZ_W + SZ_X);
    short* Vb = (short*)(ws + SZ_X + 3 * SZ_W + 2 * SZ_X);
    short* Vt = (short*)(ws + SZ_X + 3 * SZ_W + 3 * SZ_X);

    cvt_val_kernel<<<dim3((MROWS * DMODEL) / 4 / 256), dim3(256), 0, stream>>>(val, X);
    cvt_w_kernel<<<dim3(3, 96, 3), dim3(256), 0, stream>>>(Wq, Wk, Wv, WT);
    gemm_qkv_kernel<<<dim3(DMODEL / 128, MROWS / 128, 3), dim3(256), 0, stream>>>(
        X, WT, bq, bk, bv, Qb, Kb, Vb);
    transpose_v_kernel<<<dim3(NBATCH * NH, S_LEN / 64), dim3(256), 0, stream>>>(Vb, Vt);
    attn_kernel<<<dim3(S_LEN / QB, NBATCH * NH), dim3(512), 0, stream>>>(Qb, Kb, Vt, out);
}

// Round 3
// 100.445 us; speedup vs baseline: 1.4322x; 1.0610x over previous
//
#include <hip/hip_runtime.h>
#include <stdint.h>

typedef __attribute__((ext_vector_type(8))) short short8;
typedef __attribute__((ext_vector_type(4))) short short4v;
typedef __attribute__((ext_vector_type(4))) float f32x4;
typedef __attribute__((ext_vector_type(2))) unsigned int uint2v;

#define S_LEN 4096
#define NBATCH 2
#define DMODEL 768
#define NH 12
#define HD 64
#define MROWS (S_LEN * NBATCH)   // 8192

__device__ __forceinline__ unsigned short f2bf(float f) {
    unsigned int u = __builtin_bit_cast(unsigned int, f);
    u += 0x7fffu + ((u >> 16) & 1u);       // round-to-nearest-even
    return (unsigned short)(u >> 16);
}

// async global->LDS, 16B per lane; LDS dst is wave-uniform base + lane*16
#define GLDS16(gp, lp) __builtin_amdgcn_global_load_lds( \
    (const __attribute__((address_space(1))) void*)(gp), \
    (__attribute__((address_space(3))) void*)(lp), 16, 0, 0)

// ---------------- kernel 1: val fp32 -> X bf16 (8192 x 768) ----------------
__global__ __launch_bounds__(256) void cvt_val_kernel(const float* __restrict__ in,
                                                      short* __restrict__ out) {
    size_t i = (size_t)blockIdx.x * 256 + threadIdx.x;
    const f32x4 v = *(const f32x4*)(in + i * 4);
    short4v o;
    o.x = (short)f2bf(v.x); o.y = (short)f2bf(v.y);
    o.z = (short)f2bf(v.z); o.w = (short)f2bf(v.w);
    *(short4v*)(out + i * 4) = o;
}

// ------------- kernel 2: W fp32 (K x N) -> WT bf16 (N x K), 3 weights -------------
__global__ __launch_bounds__(256) void cvt_w_kernel(const float* __restrict__ Wq,
                                                    const float* __restrict__ Wk,
                                                    const float* __restrict__ Wv,
                                                    short* __restrict__ WT) {
    const int z = blockIdx.z;
    const float* W = (z == 0) ? Wq : ((z == 1) ? Wk : Wv);
    const int n  = blockIdx.x * 256 + threadIdx.x;
    const int k0 = blockIdx.y * 8;
    short8 o;
#pragma unroll
    for (int i = 0; i < 8; ++i)
        o[i] = (short)f2bf(W[(size_t)(k0 + i) * DMODEL + n]);
    *(short8*)(WT + (size_t)z * DMODEL * DMODEL + (size_t)n * DMODEL + k0) = o;
}

// ------- kernel 3: QKV GEMM, 128x128 tile, BK=32, 3-deep glds pipeline -------
// Counted vmcnt(4) + raw s_barrier: tiles t+1,t+2 stay in flight across the
// barrier (T4); one barrier per K-step. Epilogue repacks C through LDS for
// coalesced short8 stores.
#define NT 24   // 768/32 K-steps
__global__ __launch_bounds__(256) void gemm_qkv_kernel(
    const short* __restrict__ X, const short* __restrict__ WT,
    const float* __restrict__ bq, const float* __restrict__ bk, const float* __restrict__ bv,
    short* __restrict__ Q, short* __restrict__ K, short* __restrict__ V)
{
    __shared__ __align__(16) short SMEM[24576];   // 48 KB: A[3][4096] | B[3][4096]; reused for C
    short* As = SMEM;
    short* Bs = SMEM + 12288;

    const int z  = blockIdx.z;
    const int n0 = blockIdx.x * 128;
    const int m0 = blockIdx.y * 128;
    const int tid = threadIdx.x;
    const int lane = tid & 63;
    const int wid  = tid >> 6;

    const short* W    = WT + (size_t)z * DMODEL * DMODEL;
    const float* bias = (z == 0) ? bq : ((z == 1) ? bk : bv);
    short*       OUT  = (z == 0) ? Q  : ((z == 1) ? K  : V);

    const f32x4 zero4 = {0.f, 0.f, 0.f, 0.f};
    f32x4 acc[4][4];
#pragma unroll
    for (int i = 0; i < 4; ++i)
#pragma unroll
        for (int j = 0; j < 4; ++j) acc[i][j] = zero4;

    // staging: wave covers 32 rows (2 issues of 16); lane -> (row = l>>2, col = (l&3)*8)
    const int lr = lane >> 2;
    const int lc = (lane & 3) * 8;
    const short* gA = X + (size_t)(m0 + wid * 32 + lr) * DMODEL + lc;
    const short* gB = W + (size_t)(n0 + wid * 32 + lr) * DMODEL + lc;

    const int fr = lane & 15, kg = lane >> 4;
    const int wr = (wid >> 1) * 64, wc = (wid & 1) * 64;

#define STAGE(buf, kt) do { \
        GLDS16(gA + (kt),               As + (buf) * 4096 + wid * 1024);        \
        GLDS16(gA + 16 * DMODEL + (kt), As + (buf) * 4096 + wid * 1024 + 512);  \
        GLDS16(gB + (kt),               Bs + (buf) * 4096 + wid * 1024);        \
        GLDS16(gB + 16 * DMODEL + (kt), Bs + (buf) * 4096 + wid * 1024 + 512);  \
    } while (0)

    STAGE(0, 0);
    STAGE(1, 32);
    for (int t = 0; t < NT; ++t) {
        // per-wave wait for OWN tile-t loads (4 oldest); keep t+1,t+2 in flight
        if (t + 2 < NT) { asm volatile("s_waitcnt vmcnt(4)" ::: "memory"); }
        else            { asm volatile("s_waitcnt vmcnt(0)" ::: "memory"); }
        __builtin_amdgcn_sched_barrier(0);
        __builtin_amdgcn_s_barrier();      // all waves waited -> tile t fully in LDS
        __builtin_amdgcn_sched_barrier(0);
        if (t + 2 < NT) STAGE((t + 2) % 3, (t + 2) * 32);   // WAR-safe post-barrier

        const short* Ab = As + (t % 3) * 4096;
        const short* Bb = Bs + (t % 3) * 4096;
        short8 af[4], bfv[4];
#pragma unroll
        for (int mi = 0; mi < 4; ++mi)
            af[mi] = *(const short8*)(Ab + (wr + mi * 16 + fr) * 32 + kg * 8);
#pragma unroll
        for (int ni = 0; ni < 4; ++ni)
            bfv[ni] = *(const short8*)(Bb + (wc + ni * 16 + fr) * 32 + kg * 8);
        __builtin_amdgcn_s_setprio(1);
#pragma unroll
        for (int mi = 0; mi < 4; ++mi)
#pragma unroll
            for (int ni = 0; ni < 4; ++ni)
                acc[mi][ni] = __builtin_amdgcn_mfma_f32_16x16x32_bf16(
                    af[mi], bfv[ni], acc[mi][ni], 0, 0, 0);
        __builtin_amdgcn_s_setprio(0);
    }
#undef STAGE

    __syncthreads();                        // staging LDS dead; repurpose for C tile
    const float scale = (z == 0) ? 0.125f : 1.0f;   // q /= sqrt(64)
    float bval[4];
#pragma unroll
    for (int ni = 0; ni < 4; ++ni) bval[ni] = bias[n0 + wc + ni * 16 + fr];

    short* Cs = SMEM;                       // [128][136] bf16
#pragma unroll
    for (int mi = 0; mi < 4; ++mi)
#pragma unroll
        for (int ni = 0; ni < 4; ++ni)
#pragma unroll
            for (int r = 0; r < 4; ++r)
                Cs[(wr + mi * 16 + 4 * kg + r) * 136 + (wc + ni * 16 + fr)] =
                    (short)f2bf((acc[mi][ni][r] + bval[ni]) * scale);
    __syncthreads();

#pragma unroll
    for (int i = 0; i < 8; ++i) {           // 2048 chunks of 8 elems, coalesced
        const int flat = i * 256 + tid;
        const int row = flat >> 4, c8 = (flat & 15) * 8;
        const int gm = m0 + row, gn = n0 + c8;
        const int s = gm >> 1, bb = gm & 1, hh = gn >> 6, e0 = gn & 63;
        *(short8*)(&OUT[((size_t)(bb * NH + hh) * S_LEN + s) * HD + e0]) =
            *(const short8*)(&Cs[row * 136 + c8]);
    }
}

// ---------------- kernel 4: V [bh][s][e] -> Vt [bh][e][s] ----------------
__global__ __launch_bounds__(256) void transpose_v_kernel(const short* __restrict__ V,
                                                          short* __restrict__ Vt) {
    __shared__ __align__(16) short T[64][72];
    const int bh = blockIdx.x;
    const int s0 = blockIdx.y * 64;
    const int t  = threadIdx.x;
    const short* Vb  = V  + (size_t)bh * S_LEN * HD;
    short*       Vtb = Vt + (size_t)bh * HD * S_LEN;

    const int sl = t >> 3, e0 = (t & 7) * 8;
#pragma unroll
    for (int i = 0; i < 2; ++i) {
        short8 v = *(const short8*)(Vb + (size_t)(s0 + sl + i * 32) * HD + e0);
        *(short8*)(&T[sl + i * 32][e0]) = v;
    }
    __syncthreads();
    const int e  = t & 63;
    const int sb = (t >> 6) * 16;
    short vv[16];
#pragma unroll
    for (int j = 0; j < 16; ++j) vv[j] = T[sb + j][e];
    short8 a, b;
#pragma unroll
    for (int j = 0; j < 8; ++j) { a[j] = vv[j]; b[j] = vv[8 + j]; }
    *(short8*)(Vtb + (size_t)e * S_LEN + s0 + sb)     = a;
    *(short8*)(Vtb + (size_t)e * S_LEN + s0 + sb + 8) = b;
}

// ---------------- kernel 5: banded causal attention, 8 waves x 16 queries ----------------
// Block: 128 queries [q0,q0+128), staged keys [q0-256, q0+128) = 384.
// Swapped QK^T: D = K*Q^T -> col=query(fr), row=key(4g+r). Exactly 17 key-tiles/wave.
#define QB   128
#define KWIN 384
#define KST  72     // K LDS row stride (elems): 144B -> 4-bank rotation per row
#define VST  392    // Vt LDS row stride: 784B -> 4-bank rotation per row
#define PCST 40     // P chunk buffer row stride (80B, 16B-aligned rows)

__global__ __launch_bounds__(512, 2) void attn_kernel(
    const short* __restrict__ Q, const short* __restrict__ K,
    const short* __restrict__ Vt, float* __restrict__ out)
{
    __shared__ __align__(16) short Ks[KWIN * KST];        // 55296 B
    __shared__ __align__(16) short Vs[HD * VST];          // 50176 B
    __shared__ __align__(16) short Pc[8][2][16 * PCST];   // 20480 B  (per-wave ping-pong)

    const int tid = threadIdx.x, lane = tid & 63, wid = tid >> 6;
    const int q0 = blockIdx.x * QB;
    const int bh = blockIdx.y;
    const int bb = bh / NH, hh = bh % NH;
    const int fr = lane & 15, g = lane >> 4;
    const int kstart = q0 - 256;

    const short* Qb = Q  + (size_t)bh * S_LEN * HD;
    const short* Kb = K  + (size_t)bh * S_LEN * HD;
    const short* Vb = Vt + (size_t)bh * HD * S_LEN;

    // ---- cooperative staging (coalesced 16B segments) ----
#pragma unroll
    for (int it = 0; it < 6; ++it) {                 // K: 384 rows x 64 elems
        const int seg = it * 512 + tid;
        const int row = seg >> 3, c8 = (seg & 7) * 8;
        int sr = kstart + row; sr = sr < 0 ? 0 : sr;  // garbage rows masked later
        *(short8*)(Ks + row * KST + c8) = *(const short8*)(Kb + (size_t)sr * HD + c8);
    }
#pragma unroll
    for (int it = 0; it < 6; ++it) {                 // Vt: 64 rows x 384 key-cols
        const int seg = it * 512 + tid;
        const int row = seg / 48, cc = seg % 48;
        int sk = kstart + cc * 8; sk = sk < 0 ? 0 : sk;
        *(short8*)(Vs + row * VST + cc * 8) = *(const short8*)(Vb + (size_t)row * S_LEN + sk);
    }
    __syncthreads();

    // ---- Q fragments (B-operand: col=query=fr, k=8g+i) ----
    const int qrow = q0 + wid * 16 + fr;
    const short8 qa0 = *(const short8*)(Qb + (size_t)qrow * HD + g * 8);
    const short8 qa1 = *(const short8*)(Qb + (size_t)qrow * HD + 32 + g * 8);

    // ---- QK^T: 17 tiles ----
    float sc[17][4];
#pragma unroll
    for (int t = 0; t < 17; ++t) {
        const short* kr = Ks + ((wid + t) * 16 + fr) * KST;   // A row = key
        const short8 a0 = *(const short8*)(kr + g * 8);
        const short8 a1 = *(const short8*)(kr + 32 + g * 8);
        f32x4 d = {0.f, 0.f, 0.f, 0.f};
        d = __builtin_amdgcn_mfma_f32_16x16x32_bf16(a0, qa0, d, 0, 0, 0);
        d = __builtin_amdgcn_mfma_f32_16x16x32_bf16(a1, qa1, d, 0, 0, 0);
        const int gk0 = kstart + (wid + t) * 16 + 4 * g;      // global key (+r)
#pragma unroll
        for (int r = 0; r < 4; ++r) {
            const int dd = 256 + fr - 16 * t - 4 * g - r;     // query - key
            const bool ok = (dd >= 0) & (dd <= 256) & (gk0 + r >= 0);
            sc[t][r] = ok ? d[r] : -1e30f;
        }
    }

    // ---- softmax max (row = query = fr; reduce across g-groups) ----
    float mx = -1e30f;
#pragma unroll
    for (int t = 0; t < 17; ++t)
#pragma unroll
        for (int r = 0; r < 4; ++r) mx = fmaxf(mx, sc[t][r]);
    mx = fmaxf(mx, __shfl_xor(mx, 16));
    mx = fmaxf(mx, __shfl_xor(mx, 32));

    // ---- chunked exp + P redistribute (per-wave LDS, no barrier) + PV ----
    float sm = 0.f;
    f32x4 o[4];
#pragma unroll
    for (int et = 0; et < 4; ++et) o[et] = (f32x4){0.f, 0.f, 0.f, 0.f};

#pragma unroll
    for (int c = 0; c < 9; ++c) {
        float pv[8];
#pragma unroll
        for (int j = 0; j < 8; ++j) {
            const int t = 2 * c + (j >> 2);
            pv[j] = (t < 17) ? __expf(sc[t][j & 3] - mx) : 0.f;   // masked -> exp(-1e30)=0
            sm += pv[j];
        }
        unsigned int u0 = (unsigned)f2bf(pv[0]) | ((unsigned)f2bf(pv[1]) << 16);
        unsigned int u1 = (unsigned)f2bf(pv[2]) | ((unsigned)f2bf(pv[3]) << 16);
        unsigned int u2 = (unsigned)f2bf(pv[4]) | ((unsigned)f2bf(pv[5]) << 16);
        unsigned int u3 = (unsigned)f2bf(pv[6]) | ((unsigned)f2bf(pv[7]) << 16);
        short* pb = &Pc[wid][c & 1][0];
        *(uint2v*)(pb + fr * PCST + 4 * g)      = (uint2v){u0, u1};  // keys 4g..4g+3 (tile 2c)
        *(uint2v*)(pb + fr * PCST + 16 + 4 * g) = (uint2v){u2, u3};  // keys 16+4g..  (tile 2c+1)
        const short8 pa = *(const short8*)(pb + fr * PCST + 8 * g);  // A-frag: q=fr, k=8g..
        int ka = wid * 16 + 32 * c + 8 * g;
        ka = ka > KWIN - 8 ? KWIN - 8 : ka;        // clamped lanes have P=0
#pragma unroll
        for (int et = 0; et < 4; ++et) {
            const short8 vb = *(const short8*)(Vs + (et * 16 + fr) * VST + ka);
            o[et] = __builtin_amdgcn_mfma_f32_16x16x32_bf16(pa, vb, o[et], 0, 0, 0);
        }
    }

    sm += __shfl_xor(sm, 16);
    sm += __shfl_xor(sm, 32);
    const float inv = 1.0f / sm;                   // valid for query = fr
    float inv4[4];
#pragma unroll
    for (int r = 0; r < 4; ++r) inv4[r] = __shfl(inv, 4 * g + r);   // PV D-row = query 4g+r

#pragma unroll
    for (int et = 0; et < 4; ++et)
#pragma unroll
        for (int r = 0; r < 4; ++r) {
            const int qi = q0 + wid * 16 + 4 * g + r;
            const int dd = hh * HD + et * 16 + fr;
            out[((size_t)qi * NBATCH + bb) * DMODEL + dd] = o[et][r] * inv4[r];
        }
}

extern "C" void kernel_launch(void* const* d_in, const int* in_sizes, int n_in,
                              void* d_out, int out_size, void* d_ws, size_t ws_size,
                              hipStream_t stream) {
    (void)in_sizes; (void)n_in; (void)out_size; (void)ws_size;
    const float* val = (const float*)d_in[0];
    const float* Wq  = (const float*)d_in[1];
    const float* bq  = (const float*)d_in[2];
    const float* Wk  = (const float*)d_in[3];
    const float* bk  = (const float*)d_in[4];
    const float* Wv  = (const float*)d_in[5];
    const float* bv  = (const float*)d_in[6];
    float* out = (float*)d_out;

    char* ws = (char*)d_ws;
    const size_t SZ_X  = (size_t)MROWS * DMODEL * 2;
    const size_t SZ_W  = (size_t)DMODEL * DMODEL * 2;
    short* X  = (short*)(ws);
    short* WT = (short*)(ws + SZ_X);
    short* Qb = (short*)(ws + SZ_X + 3 * SZ_W);
    short* Kb = (short*)(ws + SZ_X + 3 * SZ_W + SZ_X);
    short* Vb = (short*)(ws + SZ_X + 3 * SZ_W + 2 * SZ_X);
    short* Vt = (short*)(ws + SZ_X + 3 * SZ_W + 3 * SZ_X);

    cvt_val_kernel<<<dim3((MROWS * DMODEL) / 4 / 256), dim3(256), 0, stream>>>(val, X);
    cvt_w_kernel<<<dim3(3, 96, 3), dim3(256), 0, stream>>>(Wq, Wk, Wv, WT);
    gemm_qkv_kernel<<<dim3(DMODEL / 128, MROWS / 128, 3), dim3(256), 0, stream>>>(
        X, WT, bq, bk, bv, Qb, Kb, Vb);
    transpose_v_kernel<<<dim3(NBATCH * NH, S_LEN / 64), dim3(256), 0, stream>>>(Vb, Vt);
    attn_kernel<<<dim3(S_LEN / QB, NBATCH * NH), dim3(512), 0, stream>>>(Qb, Kb, Vt, out);
}